// Round 6
// baseline (204.622 us; speedup 1.0000x reference)
//
#include <hip/hip_runtime.h>
#include <hip/hip_bf16.h>

#define IN_F 1024
#define OUT_F 1024
#define KTOT (IN_F * 9)   // 9216: channel-major, k = c*1024 + i, c=0 is silu
#define M_ROWS 8192

#define BM 256
#define BN 128
#define BK 64
#define NT (KTOT / BK)    // 144 K-tiles

typedef short bf16x8 __attribute__((ext_vector_type(8)));
typedef int   i32x4  __attribute__((ext_vector_type(4)));
typedef float f32x4  __attribute__((ext_vector_type(4)));

#define AS1 __attribute__((address_space(1)))
#define AS3 __attribute__((address_space(3)))

// ---------------------------------------------------------------- basis eval
__device__ __forceinline__ void kan_basis_fast(
    float xv, const float* __restrict__ g,
    const float* __restrict__ inv1, const float* __restrict__ inv2,
    const float* __restrict__ inv3, float* __restrict__ out) {
  float b[11];
#pragma unroll
  for (int j = 0; j < 11; ++j)
    b[j] = (xv >= g[j] && xv < g[j + 1]) ? 1.0f : 0.0f;
#pragma unroll
  for (int j = 0; j < 10; ++j)
    b[j] = (xv - g[j]) * inv1[j] * b[j] + (g[j + 2] - xv) * inv1[j + 1] * b[j + 1];
#pragma unroll
  for (int j = 0; j < 9; ++j)
    b[j] = (xv - g[j]) * inv2[j] * b[j] + (g[j + 3] - xv) * inv2[j + 1] * b[j + 1];
#pragma unroll
  for (int j = 0; j < 8; ++j)
    b[j] = (xv - g[j]) * inv3[j] * b[j] + (g[j + 4] - xv) * inv3[j + 1] * b[j + 1];
#pragma unroll
  for (int j = 0; j < 8; ++j) out[j] = b[j];
}

// ------------------------------------------------- A expansion (fp32 -> bf16)
__global__ __launch_bounds__(256) void expand_a(
    const float* __restrict__ x, const float* __restrict__ grid,
    __hip_bfloat16* __restrict__ A, int row0, int nrows) {
  int t = blockIdx.x * 256 + threadIdx.x;
  int n = t >> 7;                  // 128 threads per row
  if (n >= nrows) return;
  int i0 = (t & 127) * 8;

  float g[12];
  const float* gp = grid + (size_t)i0 * 12;   // rows identical by construction
#pragma unroll
  for (int j = 0; j < 12; ++j) g[j] = gp[j];
  float inv1[11], inv2[10], inv3[9];
#pragma unroll
  for (int j = 0; j < 11; ++j) inv1[j] = 1.0f / (g[j + 1] - g[j]);
#pragma unroll
  for (int j = 0; j < 10; ++j) inv2[j] = 1.0f / (g[j + 2] - g[j]);
#pragma unroll
  for (int j = 0; j < 9; ++j)  inv3[j] = 1.0f / (g[j + 3] - g[j]);

  const float* xp = x + (size_t)(row0 + n) * IN_F + i0;
  float xs[8];
  *(f32x4*)&xs[0] = *(const f32x4*)xp;
  *(f32x4*)&xs[4] = *(const f32x4*)(xp + 4);

  bf16x8 out[9];
#pragma unroll
  for (int j = 0; j < 8; ++j) {
    float xv = xs[j];
    float bas[8];
    kan_basis_fast(xv, g, inv1, inv2, inv3, bas);
    float s = xv / (1.0f + __expf(-xv));
    out[0][j] = (short)__bfloat16_as_ushort(__float2bfloat16(s));
#pragma unroll
    for (int c = 0; c < 8; ++c)
      out[c + 1][j] = (short)__bfloat16_as_ushort(__float2bfloat16(bas[c]));
  }
  __hip_bfloat16* dst = A + (size_t)n * KTOT + i0;
#pragma unroll
  for (int c = 0; c < 9; ++c)
    *(bf16x8*)(dst + (size_t)c * IN_F) = out[c];
}

// --------------------------------------------------- B packing (fp32 -> bf16)
__global__ __launch_bounds__(256) void pack_b(
    const float* __restrict__ bw, const float* __restrict__ sw,
    const float* __restrict__ sc, __hip_bfloat16* __restrict__ B) {
  int t = blockIdx.x * 256 + threadIdx.x;   // one per (o, i0/8): 1024*128
  if (t >= OUT_F * 128) return;
  int o = t >> 7;
  int i0 = (t & 127) * 8;

  float bwv[8], scv[8];
  const float* bp = bw + (size_t)o * IN_F + i0;
  const float* sp = sc + (size_t)o * IN_F + i0;
  *(f32x4*)&bwv[0] = *(const f32x4*)bp;
  *(f32x4*)&bwv[4] = *(const f32x4*)(bp + 4);
  *(f32x4*)&scv[0] = *(const f32x4*)sp;
  *(f32x4*)&scv[4] = *(const f32x4*)(sp + 4);

  bf16x8 out[9];
#pragma unroll
  for (int j = 0; j < 8; ++j) {
    out[0][j] = (short)__bfloat16_as_ushort(__float2bfloat16(bwv[j]));
    const float* swp = sw + ((size_t)o * IN_F + i0 + j) * 8;
    float swv[8];
    *(f32x4*)&swv[0] = *(const f32x4*)swp;
    *(f32x4*)&swv[4] = *(const f32x4*)(swp + 4);
#pragma unroll
    for (int c = 0; c < 8; ++c)
      out[c + 1][j] = (short)__bfloat16_as_ushort(__float2bfloat16(swv[c] * scv[j]));
  }
  __hip_bfloat16* dst = B + (size_t)o * KTOT + i0;
#pragma unroll
  for (int c = 0; c < 9; ++c)
    *(bf16x8*)(dst + (size_t)c * IN_F) = out[c];
}

// -------------------------------------------------------------- bf16 GEMM BT
// 256x128 tile, BK=64, 4 waves @ 128x64 each (LDS traffic 176->144 KB/tile).
// Register-pipelined: fa/fb hold kk0(t) read during MFMA-kk1(t-1); per tile:
// {read kk1(t); stage t+2; lgkm(12); MFMA kk0; lgkm(0); vmcnt(12); barrier;
// read kk0(t+1); MFMA kk1}. One barrier/tile; 3-slot LDS ring staged 2 ahead.
// T2 swizzle both-sides (pre-swizzled global src + swizzled ds_read addr).

__device__ __forceinline__ void gld16(const __hip_bfloat16* g, __hip_bfloat16* l) {
  __builtin_amdgcn_global_load_lds((AS1 void*)g, (AS3 void*)l, 16, 0, 0);
}

// inline-asm LDS read: opaque to alias analysis -> no compiler vmcnt(0) drain
__device__ __forceinline__ bf16x8 dsr128(uint32_t addr) {
  i32x4 r;
  asm volatile("ds_read_b128 %0, %1" : "=v"(r) : "v"(addr));
  return __builtin_bit_cast(bf16x8, r);
}

#define SB __builtin_amdgcn_sched_barrier(0)

#define READ_FRAGS(dA, dB, slot, h) do {                                   \
    uint32_t aS_ = aBase + (uint32_t)(slot) * (BM * BK * 2);               \
    uint32_t bS_ = bBase + (uint32_t)(slot) * (BN * BK * 2);               \
    _Pragma("unroll")                                                      \
    for (int m_ = 0; m_ < 8; ++m_) dA[m_] = dsr128(aS_ + aOffB[h][m_]);    \
    _Pragma("unroll")                                                      \
    for (int n_ = 0; n_ < 4; ++n_) dB[n_] = dsr128(bS_ + bOffB[h][n_]);    \
  } while (0)

#define MFMA_BURST(sA, sB) do {                                            \
    __builtin_amdgcn_s_setprio(1);                                         \
    _Pragma("unroll")                                                      \
    for (int m_ = 0; m_ < 8; ++m_)                                         \
      _Pragma("unroll")                                                    \
      for (int n_ = 0; n_ < 4; ++n_)                                       \
        acc[m_][n_] = __builtin_amdgcn_mfma_f32_16x16x32_bf16(             \
            sA[m_], sB[n_], acc[m_][n_], 0, 0, 0);                         \
    __builtin_amdgcn_s_setprio(0);                                         \
  } while (0)

#define STAGE_T(slot, koff) do {                                           \
    __hip_bfloat16* asD_ = &As[slot][0];                                   \
    __hip_bfloat16* bsD_ = &Bs[slot][0];                                   \
    _Pragma("unroll")                                                      \
    for (int j_ = 0; j_ < 8; ++j_)                                         \
      gld16(aSrc0 + (size_t)j_ * 32 * KTOT + (koff), asD_ + j_ * 2048 + wv * 512); \
    _Pragma("unroll")                                                      \
    for (int j_ = 0; j_ < 4; ++j_)                                         \
      gld16(bSrc0 + (size_t)j_ * 32 * KTOT + (koff), bsD_ + j_ * 2048 + wv * 512); \
  } while (0)

__global__ __launch_bounds__(256, 1) void gemm_v6(
    const __hip_bfloat16* __restrict__ A, const __hip_bfloat16* __restrict__ B,
    float* __restrict__ C) {
  __shared__ __align__(16) __hip_bfloat16 As[3][BM * BK];  // 3 x 32 KB
  __shared__ __align__(16) __hip_bfloat16 Bs[3][BN * BK];  // 3 x 16 KB

  // T1 bijective XCD swizzle: 8 bn-blocks sharing an A-panel on one XCD
  const int nwg = gridDim.x;            // (M/256)*8, %8 == 0
  const int q = nwg >> 3;
  const int L = (blockIdx.x & 7) * q + (blockIdx.x >> 3);
  const int bm = L >> 3, bn = L & 7;

  const int tid = threadIdx.x;
  const int lane = tid & 63;
  const int wv = tid >> 6;            // 0..3
  const int wm = wv >> 1;             // 0..1 (128-row group)
  const int wn = wv & 1;              // 0..1 (64-col group)
  const int l15 = lane & 15, lhi = lane >> 4;

  // ---- staging: LDS linear, global source pre-swizzled (rule #21).
  // LDS chunk p = j*256 + wv*64 + lane holds global (row = p>>3,
  // colgrp = (p&7)^(row&7)); row = j*32 + wv*8 + (lane>>3), so the swizzled
  // column is j-independent: (lane&7)^((lane>>3)&7).
  const int srow = wv * 8 + (lane >> 3);
  const int scol = ((lane & 7) ^ ((lane >> 3) & 7)) * 8;
  const __hip_bfloat16* aSrc0 = A + (size_t)(bm * BM + srow) * KTOT + scol;
  const __hip_bfloat16* bSrc0 = B + (size_t)(bn * BN + srow) * KTOT + scol;

  // ---- fragment read byte-offsets (swizzled), per kk half
  const uint32_t aBase = (uint32_t)(uintptr_t)(AS3 const void*)&As[0][0];
  const uint32_t bBase = (uint32_t)(uintptr_t)(AS3 const void*)&Bs[0][0];
  uint32_t aOffB[2][8], bOffB[2][4];
#pragma unroll
  for (int h = 0; h < 2; ++h) {
#pragma unroll
    for (int m = 0; m < 8; ++m) {
      int rowA = wm * 128 + m * 16 + l15;
      aOffB[h][m] = (rowA * 64 + (((h * 4 + lhi) ^ (l15 & 7)) * 8)) * 2;
    }
#pragma unroll
    for (int n = 0; n < 4; ++n) {
      int rowB = wn * 64 + n * 16 + l15;
      bOffB[h][n] = (rowB * 64 + (((h * 4 + lhi) ^ (l15 & 7)) * 8)) * 2;
    }
  }

  f32x4 acc[8][4];
#pragma unroll
  for (int m = 0; m < 8; ++m)
#pragma unroll
    for (int n = 0; n < 4; ++n) acc[m][n] = f32x4{0.f, 0.f, 0.f, 0.f};

  bf16x8 fa[8], fb[4];   // frags for the upcoming kk0 burst
  bf16x8 ga[8], gb[4];   // frags for the upcoming kk1 burst

  // ---- prologue: stage tiles 0,1; publish slot0; preload kk0(0)
  STAGE_T(0, 0);
  STAGE_T(1, BK);
  asm volatile("s_waitcnt vmcnt(12)" ::: "memory");   // tile 0 landed
  SB;
  __builtin_amdgcn_s_barrier();
  SB;
  READ_FRAGS(fa, fb, 0, 0);                           // 12 lgkm pending
  SB;

  int cur = 0;
  for (int t = 0; t < NT - 2; ++t) {
    const int nxt = cur == 2 ? 0 : cur + 1;
    const int stg = cur == 0 ? 2 : cur - 1;
    READ_FRAGS(ga, gb, cur, 1);                       // kk1(t); pending 24
    STAGE_T(stg, (t + 2) * BK);
    SB;
    asm volatile("s_waitcnt lgkmcnt(12)" ::: "memory");  // fa/fb ready
    SB;
    MFMA_BURST(fa, fb);                               // kk0(t)
    SB;
    asm volatile("s_waitcnt lgkmcnt(0)" ::: "memory");   // ga/gb ready
    SB;
    asm volatile("s_waitcnt vmcnt(12)" ::: "memory");    // own t+1 DMA landed
    SB;
    __builtin_amdgcn_s_barrier();                     // publish slot t+1
    SB;
    READ_FRAGS(fa, fb, nxt, 0);                       // kk0(t+1); pending 12
    SB;
    MFMA_BURST(ga, gb);                               // kk1(t)
    SB;
    cur = nxt;
  }
  // t = NT-2: no staging; drain DMA fully before reading last slot
  {
    const int nxt = cur == 2 ? 0 : cur + 1;
    READ_FRAGS(ga, gb, cur, 1);
    SB;
    asm volatile("s_waitcnt lgkmcnt(12)" ::: "memory");
    SB;
    MFMA_BURST(fa, fb);
    SB;
    asm volatile("s_waitcnt lgkmcnt(0)" ::: "memory");
    SB;
    asm volatile("s_waitcnt vmcnt(0)" ::: "memory");
    SB;
    __builtin_amdgcn_s_barrier();
    SB;
    READ_FRAGS(fa, fb, nxt, 0);
    SB;
    MFMA_BURST(ga, gb);
    SB;
    cur = nxt;
  }
  // t = NT-1: tail
  {
    READ_FRAGS(ga, gb, cur, 1);
    SB;
    asm volatile("s_waitcnt lgkmcnt(12)" ::: "memory");
    SB;
    MFMA_BURST(fa, fb);
    SB;
    asm volatile("s_waitcnt lgkmcnt(0)" ::: "memory");
    SB;
    MFMA_BURST(ga, gb);
    SB;
  }

  // epilogue: C/D mapping col = lane&15, row = (lane>>4)*4 + reg [m89]
#pragma unroll
  for (int m = 0; m < 8; ++m)
#pragma unroll
    for (int n = 0; n < 4; ++n) {
      int col = bn * BN + wn * 64 + n * 16 + l15;
      int row0 = bm * BM + wm * 128 + m * 16 + lhi * 4;
#pragma unroll
      for (int j = 0; j < 4; ++j)
        C[(size_t)(row0 + j) * OUT_F + col] = acc[m][n][j];
    }
}

// ------------------------------------------------ naive fallback (insurance)
__global__ __launch_bounds__(256) void kan_naive(
    const float* __restrict__ x, const float* __restrict__ grid,
    const float* __restrict__ bw, const float* __restrict__ sw,
    const float* __restrict__ sc, float* __restrict__ out) {
  __shared__ float s_act[IN_F];
  __shared__ float s_bas[IN_F * 8];
  int n = blockIdx.x;
  for (int i = threadIdx.x; i < IN_F; i += 256) {
    float xv = x[(size_t)n * IN_F + i];
    float g[12];
    const float* gp = grid + i * 12;
#pragma unroll
    for (int t = 0; t < 12; ++t) g[t] = gp[t];
    float b[11];
#pragma unroll
    for (int j = 0; j < 11; ++j)
      b[j] = (xv >= g[j] && xv < g[j + 1]) ? 1.0f : 0.0f;
#pragma unroll
    for (int k = 1; k <= 3; ++k)
#pragma unroll
      for (int j = 0; j < 11 - k; ++j) {
        float left = (xv - g[j]) / (g[j + k] - g[j]);
        float right = (g[j + k + 1] - xv) / (g[j + k + 1] - g[j + 1]);
        b[j] = left * b[j] + right * b[j + 1];
      }
    s_act[i] = xv / (1.0f + __expf(-xv));
#pragma unroll
    for (int c = 0; c < 8; ++c) s_bas[i * 8 + c] = b[c];
  }
  __syncthreads();
  for (int o = threadIdx.x; o < OUT_F; o += 256) {
    float acc = 0.f;
    const float* bwo = bw + (size_t)o * IN_F;
    const float* swo = sw + (size_t)o * IN_F * 8;
    const float* sco = sc + (size_t)o * IN_F;
    for (int i = 0; i < IN_F; ++i) {
      acc += s_act[i] * bwo[i];
      float p = 0.f;
#pragma unroll
      for (int c = 0; c < 8; ++c) p += s_bas[i * 8 + c] * swo[i * 8 + c];
      acc += p * sco[i];
    }
    out[(size_t)n * OUT_F + o] = acc;
  }
}

// ---------------------------------------------------------------- launch
extern "C" void kernel_launch(void* const* d_in, const int* in_sizes, int n_in,
                              void* d_out, int out_size, void* d_ws, size_t ws_size,
                              hipStream_t stream) {
  const float* x  = (const float*)d_in[0];
  const float* grid = (const float*)d_in[1];
  const float* bw = (const float*)d_in[2];
  const float* sw = (const float*)d_in[3];
  const float* sc = (const float*)d_in[4];
  float* out = (float*)d_out;

  const size_t Bbytes = (size_t)OUT_F * KTOT * 2;   // 18.9 MB
  const size_t rowBytes = (size_t)KTOT * 2;         // 18 KB / A-row

  if (ws_size >= Bbytes + 256 * rowBytes) {
    __hip_bfloat16* Bp = (__hip_bfloat16*)d_ws;
    __hip_bfloat16* Ap = (__hip_bfloat16*)((char*)d_ws + Bbytes);
    size_t arows = (ws_size - Bbytes) / rowBytes;
    int chunk = (int)((arows / 256) * 256);
    if (chunk > M_ROWS) chunk = M_ROWS;

    pack_b<<<OUT_F * 128 / 256, 256, 0, stream>>>(bw, sw, sc, Bp);
    for (int r0 = 0; r0 < M_ROWS; r0 += chunk) {
      int rows = M_ROWS - r0 < chunk ? M_ROWS - r0 : chunk;   // multiple of 256
      expand_a<<<(rows * 128 + 255) / 256, 256, 0, stream>>>(x, grid, Ap, r0, rows);
      gemm_v6<<<(rows / BM) * 8, 256, 0, stream>>>(Ap, Bp, out + (size_t)r0 * OUT_F);
    }
  } else {
    kan_naive<<<M_ROWS, 256, 0, stream>>>(x, grid, bw, sw, sc, out);
  }
}

// Round 7
// 187.711 us; speedup vs baseline: 1.0901x; 1.0901x over previous
//
#include <hip/hip_runtime.h>
#include <hip/hip_bf16.h>

#define IN_F 1024
#define OUT_F 1024
#define KTOT (IN_F * 9)   // 9216: channel-major, k = c*1024 + i, c=0 is silu
#define M_ROWS 8192

#define BM 256
#define BN 128
#define BK 64
#define NT (KTOT / BK)    // 144 K-tiles

typedef short bf16x8 __attribute__((ext_vector_type(8)));
typedef int   i32x4  __attribute__((ext_vector_type(4)));
typedef float f32x4  __attribute__((ext_vector_type(4)));

#define AS1 __attribute__((address_space(1)))
#define AS3 __attribute__((address_space(3)))

// ---------------------------------------------------------------- basis eval
__device__ __forceinline__ void kan_basis_fast(
    float xv, const float* __restrict__ g,
    const float* __restrict__ inv1, const float* __restrict__ inv2,
    const float* __restrict__ inv3, float* __restrict__ out) {
  float b[11];
#pragma unroll
  for (int j = 0; j < 11; ++j)
    b[j] = (xv >= g[j] && xv < g[j + 1]) ? 1.0f : 0.0f;
#pragma unroll
  for (int j = 0; j < 10; ++j)
    b[j] = (xv - g[j]) * inv1[j] * b[j] + (g[j + 2] - xv) * inv1[j + 1] * b[j + 1];
#pragma unroll
  for (int j = 0; j < 9; ++j)
    b[j] = (xv - g[j]) * inv2[j] * b[j] + (g[j + 3] - xv) * inv2[j + 1] * b[j + 1];
#pragma unroll
  for (int j = 0; j < 8; ++j)
    b[j] = (xv - g[j]) * inv3[j] * b[j] + (g[j + 4] - xv) * inv3[j + 1] * b[j + 1];
#pragma unroll
  for (int j = 0; j < 8; ++j) out[j] = b[j];
}

// ------------------------------------------------- A expansion (fp32 -> bf16)
__global__ __launch_bounds__(256) void expand_a(
    const float* __restrict__ x, const float* __restrict__ grid,
    __hip_bfloat16* __restrict__ A, int row0, int nrows) {
  int t = blockIdx.x * 256 + threadIdx.x;
  int n = t >> 7;                  // 128 threads per row
  if (n >= nrows) return;
  int i0 = (t & 127) * 8;

  float g[12];
  const float* gp = grid + (size_t)i0 * 12;   // rows identical by construction
#pragma unroll
  for (int j = 0; j < 12; ++j) g[j] = gp[j];
  float inv1[11], inv2[10], inv3[9];
#pragma unroll
  for (int j = 0; j < 11; ++j) inv1[j] = 1.0f / (g[j + 1] - g[j]);
#pragma unroll
  for (int j = 0; j < 10; ++j) inv2[j] = 1.0f / (g[j + 2] - g[j]);
#pragma unroll
  for (int j = 0; j < 9; ++j)  inv3[j] = 1.0f / (g[j + 3] - g[j]);

  const float* xp = x + (size_t)(row0 + n) * IN_F + i0;
  float xs[8];
  *(f32x4*)&xs[0] = *(const f32x4*)xp;
  *(f32x4*)&xs[4] = *(const f32x4*)(xp + 4);

  bf16x8 out[9];
#pragma unroll
  for (int j = 0; j < 8; ++j) {
    float xv = xs[j];
    float bas[8];
    kan_basis_fast(xv, g, inv1, inv2, inv3, bas);
    float s = xv / (1.0f + __expf(-xv));
    out[0][j] = (short)__bfloat16_as_ushort(__float2bfloat16(s));
#pragma unroll
    for (int c = 0; c < 8; ++c)
      out[c + 1][j] = (short)__bfloat16_as_ushort(__float2bfloat16(bas[c]));
  }
  __hip_bfloat16* dst = A + (size_t)n * KTOT + i0;
#pragma unroll
  for (int c = 0; c < 9; ++c)
    *(bf16x8*)(dst + (size_t)c * IN_F) = out[c];
}

// --------------------------------------------------- B packing (fp32 -> bf16)
__global__ __launch_bounds__(256) void pack_b(
    const float* __restrict__ bw, const float* __restrict__ sw,
    const float* __restrict__ sc, __hip_bfloat16* __restrict__ B) {
  int t = blockIdx.x * 256 + threadIdx.x;   // one per (o, i0/8): 1024*128
  if (t >= OUT_F * 128) return;
  int o = t >> 7;
  int i0 = (t & 127) * 8;

  float bwv[8], scv[8];
  const float* bp = bw + (size_t)o * IN_F + i0;
  const float* sp = sc + (size_t)o * IN_F + i0;
  *(f32x4*)&bwv[0] = *(const f32x4*)bp;
  *(f32x4*)&bwv[4] = *(const f32x4*)(bp + 4);
  *(f32x4*)&scv[0] = *(const f32x4*)sp;
  *(f32x4*)&scv[4] = *(const f32x4*)(sp + 4);

  bf16x8 out[9];
#pragma unroll
  for (int j = 0; j < 8; ++j) {
    out[0][j] = (short)__bfloat16_as_ushort(__float2bfloat16(bwv[j]));
    const float* swp = sw + ((size_t)o * IN_F + i0 + j) * 8;
    float swv[8];
    *(f32x4*)&swv[0] = *(const f32x4*)swp;
    *(f32x4*)&swv[4] = *(const f32x4*)(swp + 4);
#pragma unroll
    for (int c = 0; c < 8; ++c)
      out[c + 1][j] = (short)__bfloat16_as_ushort(__float2bfloat16(swv[c] * scv[j]));
  }
  __hip_bfloat16* dst = B + (size_t)o * KTOT + i0;
#pragma unroll
  for (int c = 0; c < 9; ++c)
    *(bf16x8*)(dst + (size_t)c * IN_F) = out[c];
}

// -------------------------------------------------------------- bf16 GEMM BT
// 256x128 tile, BK=64, 8 waves @ 64x64 (2 waves/SIMD TLP) + register-level
// fragment double-buffer: every ds_read batch drains under an MFMA burst.
// Per tile: {read kk1(t)+stage t+2; lgkm(8); burst kk0(t); lgkm(0); vmcnt(6);
// barrier; read kk0(t+1); burst kk1(t)}. One barrier/tile, 3-slot LDS ring,
// T2 swizzle both-sides (pre-swizzled global src + swizzled ds_read addr).

__device__ __forceinline__ void gld16(const __hip_bfloat16* g, __hip_bfloat16* l) {
  __builtin_amdgcn_global_load_lds((AS1 void*)g, (AS3 void*)l, 16, 0, 0);
}

// inline-asm LDS read: opaque to alias analysis -> no compiler vmcnt(0) drain
__device__ __forceinline__ bf16x8 dsr128(uint32_t addr) {
  i32x4 r;
  asm volatile("ds_read_b128 %0, %1" : "=v"(r) : "v"(addr));
  return __builtin_bit_cast(bf16x8, r);
}

#define SB __builtin_amdgcn_sched_barrier(0)

#define READ_FRAGS(dA, dB, slot, h) do {                                   \
    uint32_t aS_ = aBase + (uint32_t)(slot) * (BM * BK * 2);               \
    uint32_t bS_ = bBase + (uint32_t)(slot) * (BN * BK * 2);               \
    _Pragma("unroll")                                                      \
    for (int m_ = 0; m_ < 4; ++m_) dA[m_] = dsr128(aS_ + aOffB[h][m_]);    \
    _Pragma("unroll")                                                      \
    for (int n_ = 0; n_ < 4; ++n_) dB[n_] = dsr128(bS_ + bOffB[h][n_]);    \
  } while (0)

#define MFMA_BURST(sA, sB) do {                                            \
    __builtin_amdgcn_s_setprio(1);                                         \
    _Pragma("unroll")                                                      \
    for (int m_ = 0; m_ < 4; ++m_)                                         \
      _Pragma("unroll")                                                    \
      for (int n_ = 0; n_ < 4; ++n_)                                       \
        acc[m_][n_] = __builtin_amdgcn_mfma_f32_16x16x32_bf16(             \
            sA[m_], sB[n_], acc[m_][n_], 0, 0, 0);                         \
    __builtin_amdgcn_s_setprio(0);                                         \
  } while (0)

#define STAGE_T(slot, koff) do {                                           \
    __hip_bfloat16* asD_ = &As[slot][0];                                   \
    __hip_bfloat16* bsD_ = &Bs[slot][0];                                   \
    _Pragma("unroll")                                                      \
    for (int j_ = 0; j_ < 4; ++j_)                                         \
      gld16(aSrc[j_] + (koff), asD_ + aDst[j_]);                           \
    _Pragma("unroll")                                                      \
    for (int j_ = 0; j_ < 2; ++j_)                                         \
      gld16(bSrc[j_] + (koff), bsD_ + bDst[j_]);                           \
  } while (0)

__global__ __launch_bounds__(512, 2) void gemm_v7(
    const __hip_bfloat16* __restrict__ A, const __hip_bfloat16* __restrict__ B,
    float* __restrict__ C) {
  __shared__ __align__(16) __hip_bfloat16 As[3][BM * BK];  // 3 x 32 KB
  __shared__ __align__(16) __hip_bfloat16 Bs[3][BN * BK];  // 3 x 16 KB

  // T1 bijective XCD swizzle: 8 bn-blocks sharing an A-panel on one XCD
  const int nwg = gridDim.x;            // (M/256)*8, %8 == 0
  const int q = nwg >> 3;
  const int L = (blockIdx.x & 7) * q + (blockIdx.x >> 3);
  const int bm = L >> 3, bn = L & 7;

  const int tid = threadIdx.x;
  const int lane = tid & 63;
  const int wv = tid >> 6;            // 0..7
  const int wm = wv >> 1;             // 0..3 (64-row group)
  const int wn = wv & 1;              // 0..1 (64-col group)
  const int l15 = lane & 15, lhi = lane >> 4;
  const int K = KTOT;

  // ---- staging: LDS linear, global source pre-swizzled (rule #21).
  // chunk p (16B) at LDS pos p holds global chunk (row=p>>3, (p&7)^(row&7)).
  const __hip_bfloat16* aSrc[4];
  const __hip_bfloat16* bSrc[2];
  int aDst[4], bDst[2];
#pragma unroll
  for (int j = 0; j < 4; ++j) {
    int p = j * 512 + wv * 64 + lane;
    int row = p >> 3;
    int col = (p & 7) ^ (row & 7);
    aSrc[j] = A + (size_t)(bm * BM + row) * K + col * 8;
    aDst[j] = (j * 512 + wv * 64) * 8;
  }
#pragma unroll
  for (int j = 0; j < 2; ++j) {
    int p = j * 512 + wv * 64 + lane;
    int row = p >> 3;
    int col = (p & 7) ^ (row & 7);
    bSrc[j] = B + (size_t)(bn * BN + row) * K + col * 8;
    bDst[j] = (j * 512 + wv * 64) * 8;
  }

  // ---- fragment read byte-offsets (swizzled), per kk half
  const uint32_t aBase = (uint32_t)(uintptr_t)(AS3 const void*)&As[0][0];
  const uint32_t bBase = (uint32_t)(uintptr_t)(AS3 const void*)&Bs[0][0];
  uint32_t aOffB[2][4], bOffB[2][4];
#pragma unroll
  for (int h = 0; h < 2; ++h)
#pragma unroll
    for (int m = 0; m < 4; ++m) {
      int rowA = wm * 64 + m * 16 + l15;
      aOffB[h][m] = (rowA * 64 + (((h * 4 + lhi) ^ (l15 & 7)) * 8)) * 2;
      int rowB = wn * 64 + m * 16 + l15;
      bOffB[h][m] = (rowB * 64 + (((h * 4 + lhi) ^ (l15 & 7)) * 8)) * 2;
    }

  f32x4 acc[4][4];
#pragma unroll
  for (int m = 0; m < 4; ++m)
#pragma unroll
    for (int n = 0; n < 4; ++n) acc[m][n] = f32x4{0.f, 0.f, 0.f, 0.f};

  bf16x8 fa[4], fb[4];   // kk0 frags (preloaded)
  bf16x8 ga[4], gb[4];   // kk1 frags

  // ---- prologue: stage tiles 0,1; publish slot0; preload kk0(0)
  STAGE_T(0, 0);
  STAGE_T(1, BK);
  asm volatile("s_waitcnt vmcnt(6)" ::: "memory");   // tile 0 landed
  SB;
  __builtin_amdgcn_s_barrier();
  SB;
  READ_FRAGS(fa, fb, 0, 0);                          // 8 lgkm pending
  SB;

  int cur = 0;
  for (int t = 0; t < NT - 2; ++t) {
    const int nxt = cur == 2 ? 0 : cur + 1;
    const int stg = cur == 0 ? 2 : cur - 1;
    READ_FRAGS(ga, gb, cur, 1);                      // kk1(t); lgkm 16
    STAGE_T(stg, (t + 2) * BK);                      // +6 vm (12 total)
    SB;
    asm volatile("s_waitcnt lgkmcnt(8)" ::: "memory");   // fa/fb ready
    SB;
    MFMA_BURST(fa, fb);                              // kk0(t); covers ga/gb
    SB;
    asm volatile("s_waitcnt lgkmcnt(0)" ::: "memory");   // ga/gb ready
    SB;
    asm volatile("s_waitcnt vmcnt(6)" ::: "memory");     // own t+1 DMA landed
    SB;
    __builtin_amdgcn_s_barrier();                    // publish slot t+1
    SB;
    READ_FRAGS(fa, fb, nxt, 0);                      // kk0(t+1); lgkm 8
    SB;
    MFMA_BURST(ga, gb);                              // kk1(t); covers fa/fb
    SB;
    cur = nxt;
  }
  // t = NT-2: no staging; drain DMA fully before publishing last slot
  {
    const int nxt = cur == 2 ? 0 : cur + 1;
    READ_FRAGS(ga, gb, cur, 1);
    SB;
    asm volatile("s_waitcnt lgkmcnt(8)" ::: "memory");
    SB;
    MFMA_BURST(fa, fb);
    SB;
    asm volatile("s_waitcnt lgkmcnt(0)" ::: "memory");
    SB;
    asm volatile("s_waitcnt vmcnt(0)" ::: "memory");
    SB;
    __builtin_amdgcn_s_barrier();
    SB;
    READ_FRAGS(fa, fb, nxt, 0);
    SB;
    MFMA_BURST(ga, gb);
    SB;
    cur = nxt;
  }
  // t = NT-1: tail
  {
    READ_FRAGS(ga, gb, cur, 1);
    SB;
    asm volatile("s_waitcnt lgkmcnt(8)" ::: "memory");
    SB;
    MFMA_BURST(fa, fb);
    SB;
    asm volatile("s_waitcnt lgkmcnt(0)" ::: "memory");
    SB;
    MFMA_BURST(ga, gb);
    SB;
  }

  // epilogue: C/D mapping col = lane&15, row = (lane>>4)*4 + reg [m89]
#pragma unroll
  for (int m = 0; m < 4; ++m)
#pragma unroll
    for (int n = 0; n < 4; ++n) {
      int col = bn * BN + wn * 64 + n * 16 + l15;
      int row0 = bm * BM + wm * 64 + m * 16 + lhi * 4;
#pragma unroll
      for (int j = 0; j < 4; ++j)
        C[(size_t)(row0 + j) * OUT_F + col] = acc[m][n][j];
    }
}

// ------------------------------------------------ naive fallback (insurance)
__global__ __launch_bounds__(256) void kan_naive(
    const float* __restrict__ x, const float* __restrict__ grid,
    const float* __restrict__ bw, const float* __restrict__ sw,
    const float* __restrict__ sc, float* __restrict__ out) {
  __shared__ float s_act[IN_F];
  __shared__ float s_bas[IN_F * 8];
  int n = blockIdx.x;
  for (int i = threadIdx.x; i < IN_F; i += 256) {
    float xv = x[(size_t)n * IN_F + i];
    float g[12];
    const float* gp = grid + i * 12;
#pragma unroll
    for (int t = 0; t < 12; ++t) g[t] = gp[t];
    float b[11];
#pragma unroll
    for (int j = 0; j < 11; ++j)
      b[j] = (xv >= g[j] && xv < g[j + 1]) ? 1.0f : 0.0f;
#pragma unroll
    for (int k = 1; k <= 3; ++k)
#pragma unroll
      for (int j = 0; j < 11 - k; ++j) {
        float left = (xv - g[j]) / (g[j + k] - g[j]);
        float right = (g[j + k + 1] - xv) / (g[j + k + 1] - g[j + 1]);
        b[j] = left * b[j] + right * b[j + 1];
      }
    s_act[i] = xv / (1.0f + __expf(-xv));
#pragma unroll
    for (int c = 0; c < 8; ++c) s_bas[i * 8 + c] = b[c];
  }
  __syncthreads();
  for (int o = threadIdx.x; o < OUT_F; o += 256) {
    float acc = 0.f;
    const float* bwo = bw + (size_t)o * IN_F;
    const float* swo = sw + (size_t)o * IN_F * 8;
    const float* sco = sc + (size_t)o * IN_F;
    for (int i = 0; i < IN_F; ++i) {
      acc += s_act[i] * bwo[i];
      float p = 0.f;
#pragma unroll
      for (int c = 0; c < 8; ++c) p += s_bas[i * 8 + c] * swo[i * 8 + c];
      acc += p * sco[i];
    }
    out[(size_t)n * OUT_F + o] = acc;
  }
}

// ---------------------------------------------------------------- launch
extern "C" void kernel_launch(void* const* d_in, const int* in_sizes, int n_in,
                              void* d_out, int out_size, void* d_ws, size_t ws_size,
                              hipStream_t stream) {
  const float* x  = (const float*)d_in[0];
  const float* grid = (const float*)d_in[1];
  const float* bw = (const float*)d_in[2];
  const float* sw = (const float*)d_in[3];
  const float* sc = (const float*)d_in[4];
  float* out = (float*)d_out;

  const size_t Bbytes = (size_t)OUT_F * KTOT * 2;   // 18.9 MB
  const size_t rowBytes = (size_t)KTOT * 2;         // 18 KB / A-row

  if (ws_size >= Bbytes + 256 * rowBytes) {
    __hip_bfloat16* Bp = (__hip_bfloat16*)d_ws;
    __hip_bfloat16* Ap = (__hip_bfloat16*)((char*)d_ws + Bbytes);
    size_t arows = (ws_size - Bbytes) / rowBytes;
    int chunk = (int)((arows / 256) * 256);
    if (chunk > M_ROWS) chunk = M_ROWS;

    pack_b<<<OUT_F * 128 / 256, 256, 0, stream>>>(bw, sw, sc, Bp);
    for (int r0 = 0; r0 < M_ROWS; r0 += chunk) {
      int rows = M_ROWS - r0 < chunk ? M_ROWS - r0 : chunk;   // multiple of 256
      expand_a<<<(rows * 128 + 255) / 256, 256, 0, stream>>>(x, grid, Ap, r0, rows);
      gemm_v7<<<(rows / BM) * 8, 512, 0, stream>>>(Ap, Bp, out + (size_t)r0 * OUT_F);
    }
  } else {
    kan_naive<<<M_ROWS, 256, 0, stream>>>(x, grid, bw, sw, sc, out);
  }
}